// Round 1
// baseline (3722.212 us; speedup 1.0000x reference)
//
#include <hip/hip_runtime.h>
#include <hip/hip_bf16.h>

// Problem constants (from reference): B=64, T=2048, IN_F=128, H1=OUT_F=64, 4H=256
#define BB 64
#define TT 2048
#define INF 128
#define HH 64
#define GG 256  // 4*H

// ---------------------------------------------------------------------------
// Kernel 1: xg1[bt][g] = sum_k x[bt][k] * W_ih1[g][k] + b_ih1[g] + b_hh1[g]
// M=131072, N=256, K=128.  64x64 tile, full-K in LDS, 4x4 register blocking.
// LDS row stride 132 (pad +4 floats): keeps 16B alignment for ds_read_b128
// and shifts banks by 4 per row -> conflict-free fragment reads.
// ---------------------------------------------------------------------------
#define LDT 132

__global__ __launch_bounds__(256) void xgemm(const float* __restrict__ X,
                                             const float* __restrict__ W,
                                             const float* __restrict__ bi,
                                             const float* __restrict__ bh,
                                             float* __restrict__ XG) {
  __shared__ __align__(16) float As[64 * LDT];
  __shared__ __align__(16) float Bs[64 * LDT];
  const int tid = threadIdx.x;
  const int nt = blockIdx.x & 3;          // 4 N-tiles of 64
  const long mt = blockIdx.x >> 2;        // 2048 M-tiles of 64

  const float4* Ag = (const float4*)(X + mt * 64 * INF);
  const float4* Bg = (const float4*)(W + (long)nt * 64 * INF);
#pragma unroll
  for (int i = 0; i < 8; ++i) {
    int idx = tid + i * 256;              // 0..2047 float4s (64 rows x 32 f4)
    int row = idx >> 5;
    int c4 = idx & 31;
    *(float4*)&As[row * LDT + c4 * 4] = Ag[idx];
    *(float4*)&Bs[row * LDT + c4 * 4] = Bg[idx];
  }
  __syncthreads();

  const int tn = tid & 15, tm = tid >> 4; // 16x16 threads of 4x4 outputs
  float acc[4][4] = {};
#pragma unroll
  for (int k4 = 0; k4 < 32; ++k4) {
    float4 a[4], bv[4];
#pragma unroll
    for (int r = 0; r < 4; ++r) a[r] = *(const float4*)&As[(tm * 4 + r) * LDT + k4 * 4];
#pragma unroll
    for (int c = 0; c < 4; ++c) bv[c] = *(const float4*)&Bs[(tn * 4 + c) * LDT + k4 * 4];
#pragma unroll
    for (int r = 0; r < 4; ++r)
#pragma unroll
      for (int c = 0; c < 4; ++c)
        acc[r][c] += a[r].x * bv[c].x + a[r].y * bv[c].y + a[r].z * bv[c].z + a[r].w * bv[c].w;
  }

  float bias[4];
#pragma unroll
  for (int c = 0; c < 4; ++c) {
    int n = nt * 64 + tn * 4 + c;
    bias[c] = bi[n] + bh[n];
  }
#pragma unroll
  for (int r = 0; r < 4; ++r) {
    float4 o;
    o.x = acc[r][0] + bias[0];
    o.y = acc[r][1] + bias[1];
    o.z = acc[r][2] + bias[2];
    o.w = acc[r][3] + bias[3];
    long m = mt * 64 + tm * 4 + r;
    *(float4*)&XG[m * GG + nt * 64 + tn * 4] = o;
  }
}

// ---------------------------------------------------------------------------
// Kernel 2: fused 2-layer LSTM recurrence + dropout masks + relu.
// One block per sequence (64 blocks, 256 threads). Thread g owns gate g of
// both layers; W_hh1/W_ih2/W_hh2 row g live in 192 VGPRs for the whole loop.
// 4 barriers per timestep (2 per layer: gates->LDS, h->LDS).
// ---------------------------------------------------------------------------
__device__ __forceinline__ float sigm(float x) { return 1.0f / (1.0f + __expf(-x)); }
__device__ __forceinline__ float tanh_f(float x) {
  float e = __expf(2.0f * x);
  return 1.0f - 2.0f / (e + 1.0f);  // safe at +/-inf
}

__global__ __launch_bounds__(256, 1) void lstm2(const float* __restrict__ XG,
                                                const float* __restrict__ Whh1,
                                                const float* __restrict__ Wih2,
                                                const float* __restrict__ Whh2,
                                                const float* __restrict__ bi2,
                                                const float* __restrict__ bh2,
                                                const float* __restrict__ m1g,
                                                const float* __restrict__ m2g,
                                                float* __restrict__ out) {
  const int b = blockIdx.x, tid = threadIdx.x;
  __shared__ __align__(16) float h1s[HH];
  __shared__ __align__(16) float x2s[HH];
  __shared__ __align__(16) float h2s[HH];
  __shared__ __align__(16) float g1s[GG];
  __shared__ __align__(16) float g2s[GG];

  // Per-thread weight rows (kept in VGPRs; all indices constant after unroll).
  float w1[HH], wi2[HH], wh2[HH];
  {
    const float4* p1 = (const float4*)(Whh1 + (long)tid * HH);
    const float4* p2 = (const float4*)(Wih2 + (long)tid * HH);
    const float4* p3 = (const float4*)(Whh2 + (long)tid * HH);
#pragma unroll
    for (int i = 0; i < 16; ++i) {
      ((float4*)w1)[i] = p1[i];
      ((float4*)wi2)[i] = p2[i];
      ((float4*)wh2)[i] = p3[i];
    }
  }
  const float bias2 = bi2[tid] + bh2[tid];

  float c1 = 0.f, c2 = 0.f, m1 = 0.f, m2 = 0.f;
  if (tid < HH) {
    m1 = m1g[b * HH + tid];
    m2 = m2g[b * HH + tid];
    h1s[tid] = 0.f;
    x2s[tid] = 0.f;
    h2s[tid] = 0.f;
  }
  __syncthreads();

  const float* xg = XG + (size_t)b * TT * GG;
  float* ob = out + (size_t)b * TT * HH;

  float xg_cur = xg[tid];  // t=0, prefetched
  for (int t = 0; t < TT; ++t) {
    // Prefetch next timestep's input-GEMM row; latency hides under this step.
    float xg_next = (t + 1 < TT) ? xg[(t + 1) * GG + tid] : 0.f;

    // ---- layer 1 gates: g = xg + h1 . Whh1[row g] ----
    float acc = xg_cur;
#pragma unroll
    for (int k = 0; k < 16; ++k) {
      float4 h4 = ((const float4*)h1s)[k];  // broadcast ds_read_b128
      acc += h4.x * w1[4 * k] + h4.y * w1[4 * k + 1] + h4.z * w1[4 * k + 2] + h4.w * w1[4 * k + 3];
    }
    g1s[tid] = acc;
    __syncthreads();

    // ---- layer 1 cell/hidden update (gate order i,f,g,o) ----
    if (tid < HH) {
      float gi = g1s[tid], gf = g1s[HH + tid], gc = g1s[2 * HH + tid], go = g1s[3 * HH + tid];
      c1 = sigm(gf) * c1 + sigm(gi) * tanh_f(gc);
      float h1 = sigm(go) * tanh_f(c1);
      h1s[tid] = h1;
      x2s[tid] = h1 * m1;  // variational dropout (pre-scaled mask)
    }
    __syncthreads();

    // ---- layer 2 gates: g = b2 + x2 . Wih2[g] + h2 . Whh2[g] ----
    float acc2 = bias2;
#pragma unroll
    for (int k = 0; k < 16; ++k) {
      float4 x4 = ((const float4*)x2s)[k];
      float4 h4 = ((const float4*)h2s)[k];
      acc2 += x4.x * wi2[4 * k] + x4.y * wi2[4 * k + 1] + x4.z * wi2[4 * k + 2] + x4.w * wi2[4 * k + 3];
      acc2 += h4.x * wh2[4 * k] + h4.y * wh2[4 * k + 1] + h4.z * wh2[4 * k + 2] + h4.w * wh2[4 * k + 3];
    }
    g2s[tid] = acc2;
    __syncthreads();

    // ---- layer 2 update + mask2 + relu + store ----
    if (tid < HH) {
      float gi = g2s[tid], gf = g2s[HH + tid], gc = g2s[2 * HH + tid], go = g2s[3 * HH + tid];
      c2 = sigm(gf) * c2 + sigm(gi) * tanh_f(gc);
      float h2 = sigm(go) * tanh_f(c2);
      h2s[tid] = h2;
      float o = h2 * m2;
      ob[t * HH + tid] = fmaxf(o, 0.f);
    }
    __syncthreads();

    xg_cur = xg_next;
  }
}

extern "C" void kernel_launch(void* const* d_in, const int* in_sizes, int n_in,
                              void* d_out, int out_size, void* d_ws, size_t ws_size,
                              hipStream_t stream) {
  (void)in_sizes; (void)n_in; (void)out_size; (void)ws_size;
  const float* x     = (const float*)d_in[0];
  const float* W_ih1 = (const float*)d_in[1];
  const float* W_hh1 = (const float*)d_in[2];
  const float* b_ih1 = (const float*)d_in[3];
  const float* b_hh1 = (const float*)d_in[4];
  const float* W_ih2 = (const float*)d_in[5];
  const float* W_hh2 = (const float*)d_in[6];
  const float* b_ih2 = (const float*)d_in[7];
  const float* b_hh2 = (const float*)d_in[8];
  const float* mask1 = (const float*)d_in[9];
  const float* mask2 = (const float*)d_in[10];
  float* out = (float*)d_out;

  float* xg1 = (float*)d_ws;  // B*T*4H fp32 = 134,217,728 bytes

  // Input-side GEMM for layer 1 over all timesteps (fully parallel).
  xgemm<<<dim3((BB * TT / 64) * 4), dim3(256), 0, stream>>>(x, W_ih1, b_ih1, b_hh1, xg1);
  // Fused sequential 2-layer LSTM + dropout + relu.
  lstm2<<<dim3(BB), dim3(256), 0, stream>>>(xg1, W_hh1, W_ih2, W_hh2, b_ih2, b_hh2,
                                            mask1, mask2, out);
}